// Round 5
// baseline (216.725 us; speedup 1.0000x reference)
//
#include <hip/hip_runtime.h>
#include <cmath>

#define BBATCH 8
#define NN 128
#define DD 128      // IN_DIM
#define CC 64       // IN_DIM_E
#define HH 8
#define KK 64
#define HK 512
#define ROWS (BBATCH*NN)     // 1024
#define MATSZ (ROWS*HK)      // 524288 elements per projection matrix

typedef __attribute__((ext_vector_type(8))) short sh8;    // 8 bf16 = 4 VGPRs
typedef __attribute__((ext_vector_type(4))) float f32x4;  // MFMA C/D

static __device__ __forceinline__ unsigned short f2bf(float f) {
    union { float f; unsigned u; } v; v.f = f;
    unsigned r = v.u + 0x7fffu + ((v.u >> 16) & 1u);   // RNE
    return (unsigned short)(r >> 16);
}
static __device__ __forceinline__ float bf2f(unsigned short u) {
    union { unsigned u; float f; } v; v.u = ((unsigned)u) << 16;
    return v.f;
}

// ws layout (floats):
//   [0 .. M)      Qh fp32 [b*n][hk]
//   [M .. 2M)     Q2 fp32 [b*n][hk]
//   [2M .. 3M)    Vt fp32 [b][h][k][j]           (transposed for phase-3 vector loads)
//   ushort* U = (ushort*)(ws + 3M):
//     [0 .. M)    Kt1 bf16 [b][h][j][k]          (pre-scaled by K^-0.5, transposed)
//     [M .. 2M)   Kt2 bf16 [b][h][j][k]
//     [2M .. +64K) Wfrag bf16 [2][8 h][8 frag][64 lane][8]  (A-operand order)

// ---------------- Kernel 1: projections + W fragment conversion ----------------
__global__ __launch_bounds__(256) void proj_kernel(
    const float* __restrict__ h,
    const float* __restrict__ Wq, const float* __restrict__ Wk,
    const float* __restrict__ Wv, const float* __restrict__ Wq2,
    const float* __restrict__ Wk2,
    const float* __restrict__ We, const float* __restrict__ We2,
    float* __restrict__ ws)
{
    const int t  = threadIdx.x;
    const int bx = blockIdx.x;
    const int by = blockIdx.y;

    if (by >= 40) {
        // ---- W -> A-fragment-order bf16 ----
        const int v = by - 40;
        const float* W = v ? We2 : We;
        unsigned short* Wfrag = (unsigned short*)(ws + 3*(size_t)MATSZ) + 2*(size_t)MATSZ
                              + (size_t)v * 32768;
        const int g   = bx * 256 + t;     // 0..4095
        const int c   = g >> 6;           // 0..63
        const int sub = g & 63;
        const int hh  = sub >> 3;
        const int k0  = (sub & 7) * 8;
        float4 w0 = *(const float4*)(W + (size_t)c*HK + hh*KK + k0);
        float4 w1 = *(const float4*)(W + (size_t)c*HK + hh*KK + k0 + 4);
        float wv[8] = {w0.x,w0.y,w0.z,w0.w,w1.x,w1.y,w1.z,w1.w};
        const int cb = c >> 5, g4 = (c >> 3) & 3, jj = c & 7;
        #pragma unroll
        for (int q = 0; q < 8; ++q) {
            int k  = k0 + q;
            int mb = k >> 4, m = k & 15;
            Wfrag[(size_t)hh*4096 + (mb*2+cb)*512 + (g4*16+m)*8 + jj] = f2bf(wv[q]);
        }
        return;
    }

    __shared__ float As[64*136];
    __shared__ float Bs[128*64];
    const int m    = by >> 3;
    const int col0 = (by & 7) * 64;
    const float* W = (m==0)?Wq:(m==1)?Wk:(m==2)?Wv:(m==3)?Wq2:Wk2;
    const float scale = (m==1 || m==4) ? 0.125f : 1.0f;
    const int row0 = bx * 64;

    for (int r = 0; r < 8; ++r) {
        int idx = t + 256*r;
        int row = idx >> 5;
        int c4  = idx & 31;
        float4 v = ((const float4*)(h + (size_t)(row0+row)*DD))[c4];
        ((float4*)(As + row*136))[c4] = v;
    }
    for (int r = 0; r < 8; ++r) {
        int idx = t + 256*r;
        int kk = idx >> 4;
        int c4 = idx & 15;
        ((float4*)Bs)[idx] = ((const float4*)(W + (size_t)kk*HK + col0))[c4];
    }
    __syncthreads();

    const int tx = t & 15, ty = t >> 4;
    float acc[4][4] = {};
    #pragma unroll 2
    for (int k4 = 0; k4 < 32; ++k4) {
        float a4[4][4], b4[4][4];
        #pragma unroll
        for (int ii = 0; ii < 4; ++ii)
            *(float4*)a4[ii] = *(const float4*)(As + (ty*4+ii)*136 + k4*4);
        #pragma unroll
        for (int kk = 0; kk < 4; ++kk)
            *(float4*)b4[kk] = ((const float4*)Bs)[(k4*4+kk)*16 + tx];
        #pragma unroll
        for (int ii = 0; ii < 4; ++ii)
            #pragma unroll
            for (int kk = 0; kk < 4; ++kk) {
                acc[ii][0] += a4[ii][kk]*b4[kk][0];
                acc[ii][1] += a4[ii][kk]*b4[kk][1];
                acc[ii][2] += a4[ii][kk]*b4[kk][2];
                acc[ii][3] += a4[ii][kk]*b4[kk][3];
            }
    }

    const int hh = by & 7;   // head index for K/V tiles (col0 = hh*64)
    if (m == 1 || m == 4) {
        // K -> bf16 transposed [b][h][j][k]
        unsigned short* Kt = (unsigned short*)(ws + 3*(size_t)MATSZ)
                           + (m==4 ? (size_t)MATSZ : 0);
        #pragma unroll
        for (int ii = 0; ii < 4; ++ii) {
            int r = row0 + ty*4 + ii;
            int bb = r >> 7, j = r & 127;
            ushort4 u;
            u.x = f2bf(acc[ii][0]*scale); u.y = f2bf(acc[ii][1]*scale);
            u.z = f2bf(acc[ii][2]*scale); u.w = f2bf(acc[ii][3]*scale);
            *(ushort4*)(Kt + ((size_t)(bb*HH+hh)*NN + j)*KK + tx*4) = u;
        }
    } else if (m == 2) {
        // V -> fp32 transposed [b][h][k][j]
        float* Vt = ws + 2*(size_t)MATSZ;
        #pragma unroll
        for (int ii = 0; ii < 4; ++ii) {
            int r = row0 + ty*4 + ii;
            int bb = r >> 7, j = r & 127;
            #pragma unroll
            for (int q = 0; q < 4; ++q)
                Vt[((size_t)(bb*HH+hh)*KK + tx*4+q)*NN + j] = acc[ii][q];
        }
    } else {
        float* outp = ws + (m==0 ? 0 : (size_t)MATSZ);
        #pragma unroll
        for (int ii = 0; ii < 4; ++ii) {
            int r = row0 + ty*4 + ii;
            float4 v = make_float4(acc[ii][0], acc[ii][1], acc[ii][2], acc[ii][3]);
            ((float4*)(outp + (size_t)r*HK + col0))[tx] = v;
        }
    }
}

// ---------------- Kernel 2: barrier-free unit loop, all operands global->reg ----------------
__global__ __launch_bounds__(256, 4) void attn_kernel(
    const float* __restrict__ e, const float* __restrict__ k_RW,
    const float* __restrict__ mask, const int* __restrict__ adj,
    const float* __restrict__ ws, float* __restrict__ out)
{
    __shared__ float sc_s[HH*NN];     // 4 KB
    __shared__ float kwm_s[NN];
    __shared__ int   ad_s[NN];

    const int t    = threadIdx.x;
    const int blk  = blockIdx.x;
    const int b    = blk >> 7;
    const int i    = blk & 127;
    const int lane = t & 63;
    const int w    = t >> 6;
    const int jl   = lane & 15;
    const int kq   = (lane >> 4) * 4;

    const float* Vt = ws + 2*(size_t)MATSZ;
    const unsigned short* U   = (const unsigned short*)(ws + 3*(size_t)MATSZ);
    const unsigned short* Wfg = U + 2*(size_t)MATSZ;

    // ---- phase 0: e-fragments into registers; kwm/adj -> LDS ----
    sh8 eF[2][2];
    const float* ep = e + (size_t)blk * (NN*CC);
    const int j0 = w*16 + jl;          // np=0 column
    const int j1 = j0 + 64;            // np=1 column
    #pragma unroll
    for (int np = 0; np < 2; ++np) {
        const int j = np ? j1 : j0;
        #pragma unroll
        for (int cb = 0; cb < 2; ++cb) {
            const int c0 = cb*32 + ((lane>>4)&3)*8;
            float a0[4], a1[4];
            *(float4*)a0 = *(const float4*)(ep + j*CC + c0);
            *(float4*)a1 = *(const float4*)(ep + j*CC + c0 + 4);
            sh8 f;
            f[0]=(short)f2bf(a0[0]); f[1]=(short)f2bf(a0[1]);
            f[2]=(short)f2bf(a0[2]); f[3]=(short)f2bf(a0[3]);
            f[4]=(short)f2bf(a1[0]); f[5]=(short)f2bf(a1[1]);
            f[6]=(short)f2bf(a1[2]); f[7]=(short)f2bf(a1[3]);
            eF[np][cb] = f;
        }
    }
    if (t < NN) {
        kwm_s[t] = k_RW[(size_t)blk*NN + t] * mask[b*NN + t];
        ad_s[t]  = adj[(size_t)blk*NN + t];
    }
    const float maski = mask[b*NN + i];
    __syncthreads();
    const int ad0 = ad_s[j0], ad1 = ad_s[j1];

    // ---- unit loop: no barriers; W/K/Q direct global->reg (L2-hot) ----
    #pragma unroll 1
    for (int unit = 0; unit < 16; ++unit) {
        const int v  = unit >> 3;
        const int hh = unit & 7;
        const unsigned short* wA = Wfg + (size_t)v*32768 + (size_t)hh*4096;
        sh8 aF[4][2];
        #pragma unroll
        for (int mb = 0; mb < 4; ++mb)
            #pragma unroll
            for (int cb = 0; cb < 2; ++cb)
                aF[mb][cb] = ((const sh8*)wA)[(mb*2+cb)*64 + lane];
        const float* Qrow = ws + (size_t)v*MATSZ + (size_t)blk*HK + hh*KK;
        float q4[4][4];
        #pragma unroll
        for (int mb = 0; mb < 4; ++mb)
            *(float4*)q4[mb] = *(const float4*)(Qrow + mb*16 + kq);
        const unsigned short* Kt = U + (size_t)v*MATSZ + (size_t)(b*HH+hh)*(NN*KK);
        const bool av = (v == 0);

        #pragma unroll
        for (int np = 0; np < 2; ++np) {
            const int j = np ? j1 : j0;
            ushort4 kv[4];
            #pragma unroll
            for (int mb = 0; mb < 4; ++mb)
                kv[mb] = *(const ushort4*)(Kt + (size_t)j*KK + mb*16 + kq);
            f32x4 acc[4];
            #pragma unroll
            for (int mb = 0; mb < 4; ++mb) acc[mb] = (f32x4){0.f,0.f,0.f,0.f};
            #pragma unroll
            for (int cb = 0; cb < 2; ++cb) {
                sh8 bF = eF[np][cb];
                #pragma unroll
                for (int mb = 0; mb < 4; ++mb)
                    acc[mb] = __builtin_amdgcn_mfma_f32_16x16x32_bf16(
                                  aF[mb][cb], bF, acc[mb], 0, 0, 0);
            }
            float p = 0.f;
            #pragma unroll
            for (int mb = 0; mb < 4; ++mb) {
                p += acc[mb][0] * (q4[mb][0] * bf2f(kv[mb].x));
                p += acc[mb][1] * (q4[mb][1] * bf2f(kv[mb].y));
                p += acc[mb][2] * (q4[mb][2] * bf2f(kv[mb].z));
                p += acc[mb][3] * (q4[mb][3] * bf2f(kv[mb].w));
            }
            p += __shfl_xor(p, 16);
            p += __shfl_xor(p, 32);
            const int ad = np ? ad1 : ad0;
            if (lane < 16 && ((ad != 0) == av)) sc_s[hh*NN + j] = p;
        }
    }
    __syncthreads();

    // ---- phase 2: exp * mask_i * mask_j * k_RW ----
    #pragma unroll
    for (int r = 0; r < 4; ++r) {
        int idx = t + 256*r;
        int j = idx & 127;
        sc_s[idx] = __expf(sc_s[idx]) * kwm_s[j] * maski;
    }
    __syncthreads();

    // ---- phase 3: per-head denom + weighted V (Vt fp32 [b][h][k][j]) ----
    const float* VTB = Vt + (size_t)b*(HH*KK*NN);
    for (int hp = 0; hp < 2; ++hp) {
        const int hh = w + hp*4;
        float d = sc_s[hh*NN + lane] + sc_s[hh*NN + 64 + lane];
        #pragma unroll
        for (int mm = 32; mm >= 1; mm >>= 1) d += __shfl_xor(d, mm);
        float accv = 0.f;
        const float* vrow = VTB + ((size_t)hh*KK + lane)*NN;
        #pragma unroll 4
        for (int j4 = 0; j4 < 32; ++j4) {
            float wa[4], vv[4];
            *(float4*)wa = ((float4*)sc_s)[hh*32 + j4];
            *(float4*)vv = ((const float4*)vrow)[j4];
            accv += wa[0]*vv[0] + wa[1]*vv[1] + wa[2]*vv[2] + wa[3]*vv[3];
        }
        out[(size_t)blk*HK + hh*KK + lane] = accv / fmaxf(d, 1e-6f);
    }
}

extern "C" void kernel_launch(void* const* d_in, const int* in_sizes, int n_in,
                              void* d_out, int out_size, void* d_ws, size_t ws_size,
                              hipStream_t stream) {
    const float* h    = (const float*)d_in[0];
    const float* e    = (const float*)d_in[1];
    const float* kRW  = (const float*)d_in[2];
    const float* mask = (const float*)d_in[3];
    const int*   adj  = (const int*)d_in[4];
    const float* Wq   = (const float*)d_in[5];
    const float* Wk   = (const float*)d_in[6];
    const float* Wv   = (const float*)d_in[7];
    const float* We   = (const float*)d_in[8];
    const float* Wq2  = (const float*)d_in[9];
    const float* Wk2  = (const float*)d_in[10];
    const float* We2  = (const float*)d_in[11];
    float* out = (float*)d_out;
    float* ws  = (float*)d_ws;   // 3*2MB f32 + 2*1MB bf16 + 128KB Wfrag ~= 8.2MB

    proj_kernel<<<dim3(16, 42), 256, 0, stream>>>(h, Wq, Wk, Wv, Wq2, Wk2, We, We2, ws);
    attn_kernel<<<dim3(1024), 256, 0, stream>>>(e, kRW, mask, adj, ws, out);
}

// Round 6
// 157.048 us; speedup vs baseline: 1.3800x; 1.3800x over previous
//
#include <hip/hip_runtime.h>
#include <cmath>

#define BBATCH 8
#define NN 128
#define DD 128      // IN_DIM
#define CC 64       // IN_DIM_E
#define HH 8
#define KK 64
#define HK 512
#define ROWS (BBATCH*NN)     // 1024
#define MATSZ (ROWS*HK)      // 524288 elements per projection matrix
#define KPAD 72              // K-row stride in LDS (ushorts): 144B = 9*16B

typedef __attribute__((ext_vector_type(8))) short sh8;    // 8 bf16 = 4 VGPRs
typedef __attribute__((ext_vector_type(4))) float f32x4;  // MFMA C/D

static __device__ __forceinline__ unsigned short f2bf(float f) {
    union { float f; unsigned u; } v; v.f = f;
    unsigned r = v.u + 0x7fffu + ((v.u >> 16) & 1u);   // RNE
    return (unsigned short)(r >> 16);
}
static __device__ __forceinline__ float bf2f(unsigned short u) {
    union { unsigned u; float f; } v; v.u = ((unsigned)u) << 16;
    return v.f;
}

// ws layout (floats):
//   [0 .. M)      Qh fp32 [b*n][hk]
//   [M .. 2M)     Q2 fp32 [b*n][hk]
//   [2M .. 3M)    Vh fp32 [b*n][hk]
//   ushort* U = (ushort*)(ws + 3M):
//     [0 .. M)     Kt1 bf16 [b][h][j][k]  (pre-scaled by K^-0.5)
//     [M .. 2M)    Kt2 bf16 [b][h][j][k]
//     [2M .. +64K) Wfrag bf16 [2][8 h][8 frag][64 lane][8]  (A-operand order)

// ---------------- Kernel 1: projections + W fragment conversion ----------------
__global__ __launch_bounds__(256) void proj_kernel(
    const float* __restrict__ h,
    const float* __restrict__ Wq, const float* __restrict__ Wk,
    const float* __restrict__ Wv, const float* __restrict__ Wq2,
    const float* __restrict__ Wk2,
    const float* __restrict__ We, const float* __restrict__ We2,
    float* __restrict__ ws)
{
    const int t  = threadIdx.x;
    const int bx = blockIdx.x;
    const int by = blockIdx.y;

    if (by >= 40) {
        // ---- W -> A-fragment-order bf16 ----
        const int v = by - 40;
        const float* W = v ? We2 : We;
        unsigned short* Wfrag = (unsigned short*)(ws + 3*(size_t)MATSZ) + 2*(size_t)MATSZ
                              + (size_t)v * 32768;
        const int g   = bx * 256 + t;     // 0..4095
        const int c   = g >> 6;           // 0..63
        const int sub = g & 63;
        const int hh  = sub >> 3;
        const int k0  = (sub & 7) * 8;
        float4 w0 = *(const float4*)(W + (size_t)c*HK + hh*KK + k0);
        float4 w1 = *(const float4*)(W + (size_t)c*HK + hh*KK + k0 + 4);
        float wv[8] = {w0.x,w0.y,w0.z,w0.w,w1.x,w1.y,w1.z,w1.w};
        const int cb = c >> 5, g4 = (c >> 3) & 3, jj = c & 7;
        #pragma unroll
        for (int q = 0; q < 8; ++q) {
            int k  = k0 + q;
            int mb = k >> 4, m = k & 15;
            Wfrag[(size_t)hh*4096 + (mb*2+cb)*512 + (g4*16+m)*8 + jj] = f2bf(wv[q]);
        }
        return;
    }

    __shared__ float As[64*136];
    __shared__ float Bs[128*64];
    const int m    = by >> 3;
    const int col0 = (by & 7) * 64;
    const float* W = (m==0)?Wq:(m==1)?Wk:(m==2)?Wv:(m==3)?Wq2:Wk2;
    const float scale = (m==1 || m==4) ? 0.125f : 1.0f;
    const int row0 = bx * 64;

    for (int r = 0; r < 8; ++r) {
        int idx = t + 256*r;
        int row = idx >> 5;
        int c4  = idx & 31;
        float4 v = ((const float4*)(h + (size_t)(row0+row)*DD))[c4];
        ((float4*)(As + row*136))[c4] = v;
    }
    for (int r = 0; r < 8; ++r) {
        int idx = t + 256*r;
        int kk = idx >> 4;
        int c4 = idx & 15;
        ((float4*)Bs)[idx] = ((const float4*)(W + (size_t)kk*HK + col0))[c4];
    }
    __syncthreads();

    const int tx = t & 15, ty = t >> 4;
    float acc[4][4] = {};
    #pragma unroll 2
    for (int k4 = 0; k4 < 32; ++k4) {
        float a4[4][4], b4[4][4];
        #pragma unroll
        for (int ii = 0; ii < 4; ++ii)
            *(float4*)a4[ii] = *(const float4*)(As + (ty*4+ii)*136 + k4*4);
        #pragma unroll
        for (int kk = 0; kk < 4; ++kk)
            *(float4*)b4[kk] = ((const float4*)Bs)[(k4*4+kk)*16 + tx];
        #pragma unroll
        for (int ii = 0; ii < 4; ++ii)
            #pragma unroll
            for (int kk = 0; kk < 4; ++kk) {
                acc[ii][0] += a4[ii][kk]*b4[kk][0];
                acc[ii][1] += a4[ii][kk]*b4[kk][1];
                acc[ii][2] += a4[ii][kk]*b4[kk][2];
                acc[ii][3] += a4[ii][kk]*b4[kk][3];
            }
    }

    const int hh = by & 7;   // head index (col0 = hh*64)
    if (m == 1 || m == 4) {
        // K -> bf16 transposed-by-head [b][h][j][k]
        unsigned short* Kt = (unsigned short*)(ws + 3*(size_t)MATSZ)
                           + (m==4 ? (size_t)MATSZ : 0);
        #pragma unroll
        for (int ii = 0; ii < 4; ++ii) {
            int r = row0 + ty*4 + ii;
            int bb = r >> 7, j = r & 127;
            ushort4 u;
            u.x = f2bf(acc[ii][0]*scale); u.y = f2bf(acc[ii][1]*scale);
            u.z = f2bf(acc[ii][2]*scale); u.w = f2bf(acc[ii][3]*scale);
            *(ushort4*)(Kt + ((size_t)(bb*HH+hh)*NN + j)*KK + tx*4) = u;
        }
    } else {
        float* outp = ws + (m==0 ? 0 : (m==3 ? (size_t)MATSZ : 2*(size_t)MATSZ));
        #pragma unroll
        for (int ii = 0; ii < 4; ++ii) {
            int r = row0 + ty*4 + ii;
            float4 v = make_float4(acc[ii][0], acc[ii][1], acc[ii][2], acc[ii][3]);
            ((float4*)(outp + (size_t)r*HK + col0))[tx] = v;
        }
    }
}

// ---------------- Kernel 2: TI=2 dbuf-staged MFMA attn ----------------
// one block per (b, i-pair); 4 waves cooperate per (v,h) unit (j split by wave).
__global__ __launch_bounds__(256, 2) void attn_kernel(
    const float* __restrict__ e, const float* __restrict__ k_RW,
    const float* __restrict__ mask, const int* __restrict__ adj,
    const float* __restrict__ ws, float* __restrict__ out)
{
    __shared__ unsigned short kb_s[2][NN*KPAD];  // 36864 B
    __shared__ unsigned short wb_s[2][4096];     // 16384 B
    __shared__ float q_s[2*2*HK];                // 8192 B  [v][il][hk]
    __shared__ float sc_s[2*HH*NN];              // 8192 B  [il][h][j]
    __shared__ float kwm_s[2*NN];
    __shared__ int   ad_s[2*NN];

    const int t    = threadIdx.x;
    const int blk  = blockIdx.x;          // 512 blocks
    const int b    = blk >> 6;
    const int i0   = (blk & 63) * 2;
    const int lane = t & 63;
    const int w    = t >> 6;
    const int jl   = lane & 15;
    const int kq   = (lane >> 4) * 4;

    const float* Vh = ws + 2*(size_t)MATSZ;
    const unsigned short* U   = (const unsigned short*)(ws + 3*(size_t)MATSZ);
    const unsigned short* Wfg = U + 2*(size_t)MATSZ;

    // ---- phase 0: e-fragments into registers; kwm/adj/Q -> LDS ----
    sh8 eF[2][2][2];   // [il][jj][cb]
    #pragma unroll
    for (int il = 0; il < 2; ++il) {
        const float* ep = e + (size_t)(b*NN + i0 + il) * (NN*CC);
        #pragma unroll
        for (int jj = 0; jj < 2; ++jj) {
            const int j = w*32 + jj*16 + jl;
            #pragma unroll
            for (int cb = 0; cb < 2; ++cb) {
                const int c0 = cb*32 + ((lane>>4)&3)*8;
                float a0[4], a1[4];
                *(float4*)a0 = *(const float4*)(ep + (size_t)j*CC + c0);
                *(float4*)a1 = *(const float4*)(ep + (size_t)j*CC + c0 + 4);
                sh8 f;
                f[0]=(short)f2bf(a0[0]); f[1]=(short)f2bf(a0[1]);
                f[2]=(short)f2bf(a0[2]); f[3]=(short)f2bf(a0[3]);
                f[4]=(short)f2bf(a1[0]); f[5]=(short)f2bf(a1[1]);
                f[6]=(short)f2bf(a1[2]); f[7]=(short)f2bf(a1[3]);
                eF[il][jj][cb] = f;
            }
        }
    }
    {   // kwm / adj (il = t>>7, j = t&127)
        const int il = t >> 7, j = t & 127;
        kwm_s[t] = k_RW[(size_t)(b*NN + i0 + il)*NN + j] * mask[b*NN + j];
        ad_s[t]  = adj[(size_t)(b*NN + i0 + il)*NN + j];
    }
    #pragma unroll
    for (int r = 0; r < 8; ++r) {   // Q: 2048 floats
        int idx = t + 256*r;
        int v  = idx >> 10;
        int il = (idx >> 9) & 1;
        int hk = idx & 511;
        q_s[idx] = ws[(size_t)v*MATSZ + (size_t)(b*NN + i0 + il)*HK + hk];
    }
    const float maskI0 = mask[b*NN + i0];
    const float maskI1 = mask[b*NN + i0 + 1];

    // initial prefetch: unit 0 (v=0, hh=0)
    const int krow = t >> 1, khalf = t & 1;
    int4 kp0, kp1, kp2, kp3, wp0, wp1;
    {
        const unsigned short* ks = U + ((size_t)(b*HH + 0)*NN + krow)*KK + khalf*32;
        kp0 = ((const int4*)ks)[0]; kp1 = ((const int4*)ks)[1];
        kp2 = ((const int4*)ks)[2]; kp3 = ((const int4*)ks)[3];
        const unsigned short* wsc = Wfg + (size_t)t*16;
        wp0 = ((const int4*)wsc)[0]; wp1 = ((const int4*)wsc)[1];
    }
    __syncthreads();

    int adR[2][2];
    #pragma unroll
    for (int il = 0; il < 2; ++il)
        #pragma unroll
        for (int jj = 0; jj < 2; ++jj)
            adR[il][jj] = ad_s[il*NN + w*32 + jj*16 + jl];

    // ---- unit loop ----
    #pragma unroll 1
    for (int unit = 0; unit < 16; ++unit) {
        const int buf = unit & 1;
        const int v   = unit >> 3;
        const int hh  = unit & 7;
        {   // commit staged regs -> LDS
            unsigned short* kd = &kb_s[buf][krow*KPAD + khalf*32];
            ((int4*)kd)[0] = kp0; ((int4*)kd)[1] = kp1;
            ((int4*)kd)[2] = kp2; ((int4*)kd)[3] = kp3;
            unsigned short* wd = &wb_s[buf][t*16];
            ((int4*)wd)[0] = wp0; ((int4*)wd)[1] = wp1;
        }
        __syncthreads();
        if (unit + 1 < 16) {   // prefetch next unit
            const int v2 = (unit+1) >> 3, h2 = (unit+1) & 7;
            const unsigned short* ks = U + (size_t)v2*MATSZ
                                     + ((size_t)(b*HH + h2)*NN + krow)*KK + khalf*32;
            kp0 = ((const int4*)ks)[0]; kp1 = ((const int4*)ks)[1];
            kp2 = ((const int4*)ks)[2]; kp3 = ((const int4*)ks)[3];
            const unsigned short* wsc = Wfg + (size_t)v2*32768 + (size_t)h2*4096 + (size_t)t*16;
            wp0 = ((const int4*)wsc)[0]; wp1 = ((const int4*)wsc)[1];
        }

        sh8 aF[4][2];
        #pragma unroll
        for (int mb = 0; mb < 4; ++mb)
            #pragma unroll
            for (int cb = 0; cb < 2; ++cb)
                aF[mb][cb] = ((const sh8*)wb_s[buf])[(mb*2+cb)*64 + lane];
        float4 ql[2][4];
        #pragma unroll
        for (int il = 0; il < 2; ++il)
            #pragma unroll
            for (int mb = 0; mb < 4; ++mb)
                ql[il][mb] = *(const float4*)&q_s[(v*2+il)*HK + hh*KK + mb*16 + kq];
        const bool av = (v == 0);

        #pragma unroll
        for (int il = 0; il < 2; ++il) {
            #pragma unroll
            for (int jj = 0; jj < 2; ++jj) {
                const int j = w*32 + jj*16 + jl;
                f32x4 acc[4];
                #pragma unroll
                for (int mb = 0; mb < 4; ++mb) acc[mb] = (f32x4){0.f,0.f,0.f,0.f};
                #pragma unroll
                for (int cb = 0; cb < 2; ++cb) {
                    sh8 bF = eF[il][jj][cb];
                    #pragma unroll
                    for (int mb = 0; mb < 4; ++mb)
                        acc[mb] = __builtin_amdgcn_mfma_f32_16x16x32_bf16(
                                      aF[mb][cb], bF, acc[mb], 0, 0, 0);
                }
                float p = 0.f;
                #pragma unroll
                for (int mb = 0; mb < 4; ++mb) {
                    ushort4 kv = *(const ushort4*)&kb_s[buf][j*KPAD + mb*16 + kq];
                    float4 q = ql[il][mb];
                    p += acc[mb][0] * (q.x * bf2f(kv.x));
                    p += acc[mb][1] * (q.y * bf2f(kv.y));
                    p += acc[mb][2] * (q.z * bf2f(kv.z));
                    p += acc[mb][3] * (q.w * bf2f(kv.w));
                }
                p += __shfl_xor(p, 16);
                p += __shfl_xor(p, 32);
                if (lane < 16 && ((adR[il][jj] != 0) == av))
                    sc_s[(il*HH + hh)*NN + j] = p;
            }
        }
    }
    __syncthreads();

    // ---- phase 2: exp * mask_i * mask_j * k_RW (global max cancels in ratio) ----
    #pragma unroll
    for (int r = 0; r < 8; ++r) {
        int idx = t + 256*r;              // (il*8+hh)*128 + j
        int il = idx >> 10;
        int j  = idx & 127;
        sc_s[idx] = __expf(sc_s[idx]) * kwm_s[il*NN + j] * (il ? maskI1 : maskI0);
    }
    __syncthreads();

    // ---- phase 3: per-(il,head) denom + weighted V (coalesced fp32 rows) ----
    for (int hp = 0; hp < 2; ++hp) {
        const int hh = w + hp*4;
        const int r0 = hh*NN, r1 = (HH + hh)*NN;
        float d0 = sc_s[r0 + lane] + sc_s[r0 + 64 + lane];
        float d1 = sc_s[r1 + lane] + sc_s[r1 + 64 + lane];
        #pragma unroll
        for (int mm = 32; mm >= 1; mm >>= 1) {
            d0 += __shfl_xor(d0, mm);
            d1 += __shfl_xor(d1, mm);
        }
        float a0 = 0.f, a1 = 0.f;
        const float* vb = Vh + (size_t)(b*NN)*HK + hh*KK + lane;
        #pragma unroll 4
        for (int j = 0; j < NN; ++j) {
            float vf = vb[(size_t)j*HK];
            a0 += sc_s[r0 + j] * vf;
            a1 += sc_s[r1 + j] * vf;
        }
        out[(size_t)(b*NN + i0    )*HK + hh*KK + lane] = a0 / fmaxf(d0, 1e-6f);
        out[(size_t)(b*NN + i0 + 1)*HK + hh*KK + lane] = a1 / fmaxf(d1, 1e-6f);
    }
}

extern "C" void kernel_launch(void* const* d_in, const int* in_sizes, int n_in,
                              void* d_out, int out_size, void* d_ws, size_t ws_size,
                              hipStream_t stream) {
    const float* h    = (const float*)d_in[0];
    const float* e    = (const float*)d_in[1];
    const float* kRW  = (const float*)d_in[2];
    const float* mask = (const float*)d_in[3];
    const int*   adj  = (const int*)d_in[4];
    const float* Wq   = (const float*)d_in[5];
    const float* Wk   = (const float*)d_in[6];
    const float* Wv   = (const float*)d_in[7];
    const float* We   = (const float*)d_in[8];
    const float* Wq2  = (const float*)d_in[9];
    const float* Wk2  = (const float*)d_in[10];
    const float* We2  = (const float*)d_in[11];
    float* out = (float*)d_out;
    float* ws  = (float*)d_ws;   // 3*2MB f32 + 2*1MB bf16 + 128KB Wfrag ~= 8.2MB

    proj_kernel<<<dim3(16, 42), 256, 0, stream>>>(h, Wq, Wk, Wv, Wq2, Wk2, We, We2, ws);
    attn_kernel<<<dim3(512), 256, 0, stream>>>(e, kRW, mask, adj, ws, out);
}

// Round 7
// 151.425 us; speedup vs baseline: 1.4312x; 1.0371x over previous
//
#include <hip/hip_runtime.h>
#include <cmath>

#define BBATCH 8
#define NN 128
#define DD 128      // IN_DIM
#define CC 64       // IN_DIM_E
#define HH 8
#define KK 64
#define HK 512
#define ROWS (BBATCH*NN)     // 1024
#define MATSZ (ROWS*HK)      // 524288 elements per projection matrix

typedef __attribute__((ext_vector_type(8))) short sh8;    // 8 bf16 = 4 VGPRs
typedef __attribute__((ext_vector_type(4))) float f32x4;  // MFMA C/D

static __device__ __forceinline__ unsigned short f2bf(float f) {
    union { float f; unsigned u; } v; v.f = f;
    unsigned r = v.u + 0x7fffu + ((v.u >> 16) & 1u);   // RNE
    return (unsigned short)(r >> 16);
}
static __device__ __forceinline__ float bf2f(unsigned short u) {
    union { unsigned u; float f; } v; v.u = ((unsigned)u) << 16;
    return v.f;
}

// ws layout (floats):
//   [0 .. M)      Qh fp32 [b*n][hk]
//   [M .. 2M)     Q2 fp32 [b*n][hk]
//   [2M .. 3M)    Vh fp32 [b*n][hk]
//   ushort* U = (ushort*)(ws + 3M):
//     [0 .. M)     Kt1 bf16 [b][h][j][k'] k-permuted: k' = (k&12)*4 + (k>>4)*4 + (k&3)
//     [M .. 2M)    Kt2 bf16 same layout   (both pre-scaled by K^-0.5)
//     [2M .. +64K) Wfrag bf16 [2][8 h][8 frag][64 lane][8]  (A-operand order)

// ---------------- Kernel 1: projections + W fragment conversion ----------------
__global__ __launch_bounds__(256) void proj_kernel(
    const float* __restrict__ h,
    const float* __restrict__ Wq, const float* __restrict__ Wk,
    const float* __restrict__ Wv, const float* __restrict__ Wq2,
    const float* __restrict__ Wk2,
    const float* __restrict__ We, const float* __restrict__ We2,
    float* __restrict__ ws)
{
    const int t  = threadIdx.x;
    const int bx = blockIdx.x;
    const int by = blockIdx.y;

    if (by >= 40) {
        // ---- W -> A-fragment-order bf16 ----
        const int v = by - 40;
        const float* W = v ? We2 : We;
        unsigned short* Wfrag = (unsigned short*)(ws + 3*(size_t)MATSZ) + 2*(size_t)MATSZ
                              + (size_t)v * 32768;
        const int g   = bx * 256 + t;     // 0..4095
        const int c   = g >> 6;           // 0..63
        const int sub = g & 63;
        const int hh  = sub >> 3;
        const int k0  = (sub & 7) * 8;
        float4 w0 = *(const float4*)(W + (size_t)c*HK + hh*KK + k0);
        float4 w1 = *(const float4*)(W + (size_t)c*HK + hh*KK + k0 + 4);
        float wv[8] = {w0.x,w0.y,w0.z,w0.w,w1.x,w1.y,w1.z,w1.w};
        const int cb = c >> 5, g4 = (c >> 3) & 3, jj = c & 7;
        #pragma unroll
        for (int q = 0; q < 8; ++q) {
            int k  = k0 + q;
            int mb = k >> 4, m = k & 15;
            Wfrag[(size_t)hh*4096 + (mb*2+cb)*512 + (g4*16+m)*8 + jj] = f2bf(wv[q]);
        }
        return;
    }

    __shared__ float As[64*136];
    __shared__ float Bs[128*64];
    const int m    = by >> 3;
    const int col0 = (by & 7) * 64;
    const float* W = (m==0)?Wq:(m==1)?Wk:(m==2)?Wv:(m==3)?Wq2:Wk2;
    const float scale = (m==1 || m==4) ? 0.125f : 1.0f;
    const int row0 = bx * 64;

    for (int r = 0; r < 8; ++r) {
        int idx = t + 256*r;
        int row = idx >> 5;
        int c4  = idx & 31;
        float4 v = ((const float4*)(h + (size_t)(row0+row)*DD))[c4];
        ((float4*)(As + row*136))[c4] = v;
    }
    for (int r = 0; r < 8; ++r) {
        int idx = t + 256*r;
        int kk = idx >> 4;
        int c4 = idx & 15;
        ((float4*)Bs)[idx] = ((const float4*)(W + (size_t)kk*HK + col0))[c4];
    }
    __syncthreads();

    const int tx = t & 15, ty = t >> 4;
    float acc[4][4] = {};
    #pragma unroll 2
    for (int k4 = 0; k4 < 32; ++k4) {
        float a4[4][4], b4[4][4];
        #pragma unroll
        for (int ii = 0; ii < 4; ++ii)
            *(float4*)a4[ii] = *(const float4*)(As + (ty*4+ii)*136 + k4*4);
        #pragma unroll
        for (int kk = 0; kk < 4; ++kk)
            *(float4*)b4[kk] = ((const float4*)Bs)[(k4*4+kk)*16 + tx];
        #pragma unroll
        for (int ii = 0; ii < 4; ++ii)
            #pragma unroll
            for (int kk = 0; kk < 4; ++kk) {
                acc[ii][0] += a4[ii][kk]*b4[kk][0];
                acc[ii][1] += a4[ii][kk]*b4[kk][1];
                acc[ii][2] += a4[ii][kk]*b4[kk][2];
                acc[ii][3] += a4[ii][kk]*b4[kk][3];
            }
    }

    const int hh = by & 7;   // head index (col0 = hh*64)
    if (m == 1 || m == 4) {
        // K -> bf16 [b][h][j][k'], k' = q4*16 + mb*4 + reg  (q4=tx&3, mb=tx>>2)
        unsigned short* Kt = (unsigned short*)(ws + 3*(size_t)MATSZ)
                           + (m==4 ? (size_t)MATSZ : 0);
        const int kperm = (tx & 3)*16 + (tx >> 2)*4;
        #pragma unroll
        for (int ii = 0; ii < 4; ++ii) {
            int r = row0 + ty*4 + ii;
            int bb = r >> 7, j = r & 127;
            ushort4 u;
            u.x = f2bf(acc[ii][0]*scale); u.y = f2bf(acc[ii][1]*scale);
            u.z = f2bf(acc[ii][2]*scale); u.w = f2bf(acc[ii][3]*scale);
            *(ushort4*)(Kt + ((size_t)(bb*HH+hh)*NN + j)*KK + kperm) = u;
        }
    } else {
        float* outp = ws + (m==0 ? 0 : (m==3 ? (size_t)MATSZ : 2*(size_t)MATSZ));
        #pragma unroll
        for (int ii = 0; ii < 4; ++ii) {
            int r = row0 + ty*4 + ii;
            float4 v = make_float4(acc[ii][0], acc[ii][1], acc[ii][2], acc[ii][3]);
            ((float4*)(outp + (size_t)r*HK + col0))[tx] = v;
        }
    }
}

// ---------------- Kernel 2: barrier-free pipelined MFMA attn (TI=2) ----------------
__global__ __launch_bounds__(256, 2) void attn_kernel(
    const float* __restrict__ e, const float* __restrict__ k_RW,
    const float* __restrict__ mask, const int* __restrict__ adj,
    const float* __restrict__ ws, float* __restrict__ out)
{
    __shared__ float q_s[2*2*HK];     // 8 KB  [v][il][hk]
    __shared__ float sc_s[2*HH*NN];   // 8 KB  [il][h][j]
    __shared__ float kwm_s[2*NN];
    __shared__ int   ad_s[2*NN];

    const int t    = threadIdx.x;
    const int blk  = blockIdx.x;          // 512 blocks
    const int b    = blk >> 6;
    const int i0   = (blk & 63) * 2;
    const int lane = t & 63;
    const int w    = t >> 6;
    const int jl   = lane & 15;
    const int q4   = lane >> 4;           // k-quad of this lane's acc rows
    const int kq   = q4 * 4;

    const float* Vh = ws + 2*(size_t)MATSZ;
    const unsigned short* U   = (const unsigned short*)(ws + 3*(size_t)MATSZ);
    const unsigned short* Wfg = U + 2*(size_t)MATSZ;

    // ---- phase 0: e-fragments into registers; kwm/adj/Q -> LDS ----
    sh8 eF[2][2][2];   // [il][jj][cb]
    #pragma unroll
    for (int il = 0; il < 2; ++il) {
        const float* ep = e + (size_t)(b*NN + i0 + il) * (NN*CC);
        #pragma unroll
        for (int jj = 0; jj < 2; ++jj) {
            const int j = w*32 + jj*16 + jl;
            #pragma unroll
            for (int cb = 0; cb < 2; ++cb) {
                const int c0 = cb*32 + q4*8;
                float a0[4], a1[4];
                *(float4*)a0 = *(const float4*)(ep + (size_t)j*CC + c0);
                *(float4*)a1 = *(const float4*)(ep + (size_t)j*CC + c0 + 4);
                sh8 f;
                f[0]=(short)f2bf(a0[0]); f[1]=(short)f2bf(a0[1]);
                f[2]=(short)f2bf(a0[2]); f[3]=(short)f2bf(a0[3]);
                f[4]=(short)f2bf(a1[0]); f[5]=(short)f2bf(a1[1]);
                f[6]=(short)f2bf(a1[2]); f[7]=(short)f2bf(a1[3]);
                eF[il][jj][cb] = f;
            }
        }
    }
    {
        const int il = t >> 7, j = t & 127;
        kwm_s[t] = k_RW[(size_t)(b*NN + i0 + il)*NN + j] * mask[b*NN + j];
        ad_s[t]  = adj[(size_t)(b*NN + i0 + il)*NN + j];
    }
    #pragma unroll
    for (int r = 0; r < 8; ++r) {   // Q: 2048 floats
        int idx = t + 256*r;
        int v  = idx >> 10;
        int il = (idx >> 9) & 1;
        int hk = idx & 511;
        q_s[idx] = ws[(size_t)v*MATSZ + (size_t)(b*NN + i0 + il)*HK + hk];
    }
    const float maskI0 = mask[b*NN + i0];
    const float maskI1 = mask[b*NN + i0 + 1];

    // pipeline register sets (W A-frags + K frags), loaded direct global->reg
    sh8  aFA[8], aFB[8];            // [mb*2+cb]
    int4 kvA[2][2], kvB[2][2];      // [jj][half]: 16 ushorts = kv[mb=0..3][reg]
    const int j0 = w*32 + jl;       // jj=0 column
    const int j1 = j0 + 16;         // jj=1 column

#define LOADU(u_, aF_, kv_)                                                     \
    {   const int v_ = (u_) >> 3, h_ = (u_) & 7;                                \
        const sh8* wA_ = (const sh8*)(Wfg + (size_t)v_*32768 + (size_t)h_*4096);\
        _Pragma("unroll")                                                       \
        for (int f_ = 0; f_ < 8; ++f_) aF_[f_] = wA_[f_*64 + lane];             \
        const unsigned short* kt_ = U + (size_t)v_*MATSZ                        \
                                  + (size_t)(b*HH + h_)*(NN*KK) + q4*16;        \
        kv_[0][0] = ((const int4*)(kt_ + (size_t)j0*KK))[0];                    \
        kv_[0][1] = ((const int4*)(kt_ + (size_t)j0*KK))[1];                    \
        kv_[1][0] = ((const int4*)(kt_ + (size_t)j1*KK))[0];                    \
        kv_[1][1] = ((const int4*)(kt_ + (size_t)j1*KK))[1];                    \
    }

#define COMPUTE(u_, aF_, kv_)                                                   \
    {   const int v_ = (u_) >> 3, h_ = (u_) & 7;                                \
        const bool av_ = (v_ == 0);                                             \
        float kf_[2][4][4];                                                     \
        _Pragma("unroll")                                                       \
        for (int jj_ = 0; jj_ < 2; ++jj_) {                                     \
            const unsigned short* kp_ = (const unsigned short*)&kv_[jj_][0];    \
            _Pragma("unroll")                                                   \
            for (int mb_ = 0; mb_ < 4; ++mb_)                                   \
                _Pragma("unroll")                                               \
                for (int r_ = 0; r_ < 4; ++r_)                                  \
                    kf_[jj_][mb_][r_] = bf2f(kp_[mb_*4 + r_]);                  \
        }                                                                       \
        _Pragma("unroll")                                                       \
        for (int il_ = 0; il_ < 2; ++il_) {                                     \
            float4 ql_[4];                                                      \
            _Pragma("unroll")                                                   \
            for (int mb_ = 0; mb_ < 4; ++mb_)                                   \
                ql_[mb_] = *(const float4*)&q_s[(v_*2+il_)*HK + h_*KK + mb_*16 + kq]; \
            f32x4 acc_[2][4];                                                   \
            _Pragma("unroll")                                                   \
            for (int jj_ = 0; jj_ < 2; ++jj_)                                   \
                _Pragma("unroll")                                               \
                for (int mb_ = 0; mb_ < 4; ++mb_)                               \
                    acc_[jj_][mb_] = (f32x4){0.f,0.f,0.f,0.f};                  \
            _Pragma("unroll")                                                   \
            for (int jj_ = 0; jj_ < 2; ++jj_)                                   \
                _Pragma("unroll")                                               \
                for (int cb_ = 0; cb_ < 2; ++cb_) {                             \
                    sh8 bF_ = eF[il_][jj_][cb_];                                \
                    _Pragma("unroll")                                           \
                    for (int mb_ = 0; mb_ < 4; ++mb_)                           \
                        acc_[jj_][mb_] = __builtin_amdgcn_mfma_f32_16x16x32_bf16( \
                            aF_[mb_*2+cb_], bF_, acc_[jj_][mb_], 0, 0, 0);      \
                }                                                               \
            _Pragma("unroll")                                                   \
            for (int jj_ = 0; jj_ < 2; ++jj_) {                                 \
                float p_ = 0.f;                                                 \
                _Pragma("unroll")                                               \
                for (int mb_ = 0; mb_ < 4; ++mb_) {                             \
                    p_ += acc_[jj_][mb_][0] * (ql_[mb_].x * kf_[jj_][mb_][0]);  \
                    p_ += acc_[jj_][mb_][1] * (ql_[mb_].y * kf_[jj_][mb_][1]);  \
                    p_ += acc_[jj_][mb_][2] * (ql_[mb_].z * kf_[jj_][mb_][2]);  \
                    p_ += acc_[jj_][mb_][3] * (ql_[mb_].w * kf_[jj_][mb_][3]);  \
                }                                                               \
                p_ += __shfl_xor(p_, 16);                                       \
                p_ += __shfl_xor(p_, 32);                                       \
                const int jc_ = jj_ ? j1 : j0;                                  \
                if (lane < 16 && ((adR[il_][jj_] != 0) == av_))                 \
                    sc_s[(il_*HH + h_)*NN + jc_] = p_;                          \
            }                                                                   \
        }                                                                       \
    }

    LOADU(0, aFA, kvA)
    LOADU(1, aFB, kvB)
    __syncthreads();

    int adR[2][2];
    #pragma unroll
    for (int il = 0; il < 2; ++il) {
        adR[il][0] = ad_s[il*NN + j0];
        adR[il][1] = ad_s[il*NN + j1];
    }

    // ---- pipelined unit loop: no barriers, 1-unit prefetch distance ----
    #pragma unroll 1
    for (int u = 0; u < 16; u += 2) {
        COMPUTE(u, aFA, kvA)
        if (u + 2 < 16) LOADU(u + 2, aFA, kvA)
        COMPUTE(u + 1, aFB, kvB)
        if (u + 3 < 16) LOADU(u + 3, aFB, kvB)
    }
    __syncthreads();

    // ---- phase 2: exp * mask_i * mask_j * k_RW (global max cancels in ratio) ----
    #pragma unroll
    for (int r = 0; r < 8; ++r) {
        int idx = t + 256*r;              // (il*8+hh)*128 + j
        int il = idx >> 10;
        int j  = idx & 127;
        sc_s[idx] = __expf(sc_s[idx]) * kwm_s[il*NN + j] * (il ? maskI1 : maskI0);
    }
    __syncthreads();

    // ---- phase 3: per-(il,head) denom + weighted V (coalesced fp32 rows) ----
    for (int hp = 0; hp < 2; ++hp) {
        const int hh = w + hp*4;
        const int r0 = hh*NN, r1 = (HH + hh)*NN;
        float d0 = sc_s[r0 + lane] + sc_s[r0 + 64 + lane];
        float d1 = sc_s[r1 + lane] + sc_s[r1 + 64 + lane];
        #pragma unroll
        for (int mm = 32; mm >= 1; mm >>= 1) {
            d0 += __shfl_xor(d0, mm);
            d1 += __shfl_xor(d1, mm);
        }
        float a0 = 0.f, a1 = 0.f;
        const float* vb = Vh + (size_t)(b*NN)*HK + hh*KK + lane;
        #pragma unroll 4
        for (int j = 0; j < NN; ++j) {
            float vf = vb[(size_t)j*HK];
            a0 += sc_s[r0 + j] * vf;
            a1 += sc_s[r1 + j] * vf;
        }
        out[(size_t)(b*NN + i0    )*HK + hh*KK + lane] = a0 / fmaxf(d0, 1e-6f);
        out[(size_t)(b*NN + i0 + 1)*HK + hh*KK + lane] = a1 / fmaxf(d1, 1e-6f);
    }
#undef LOADU
#undef COMPUTE
}

extern "C" void kernel_launch(void* const* d_in, const int* in_sizes, int n_in,
                              void* d_out, int out_size, void* d_ws, size_t ws_size,
                              hipStream_t stream) {
    const float* h    = (const float*)d_in[0];
    const float* e    = (const float*)d_in[1];
    const float* kRW  = (const float*)d_in[2];
    const float* mask = (const float*)d_in[3];
    const int*   adj  = (const int*)d_in[4];
    const float* Wq   = (const float*)d_in[5];
    const float* Wk   = (const float*)d_in[6];
    const float* Wv   = (const float*)d_in[7];
    const float* We   = (const float*)d_in[8];
    const float* Wq2  = (const float*)d_in[9];
    const float* Wk2  = (const float*)d_in[10];
    const float* We2  = (const float*)d_in[11];
    float* out = (float*)d_out;
    float* ws  = (float*)d_ws;   // 3*2MB f32 + 2*1MB bf16 + 128KB Wfrag ~= 8.2MB

    proj_kernel<<<dim3(16, 42), 256, 0, stream>>>(h, Wq, Wk, Wv, Wq2, Wk2, We, We2, ws);
    attn_kernel<<<dim3(512), 256, 0, stream>>>(e, kRW, mask, adj, ws, out);
}